// Round 7
// baseline (340.056 us; speedup 1.0000x reference)
//
#include <hip/hip_runtime.h>

typedef float f32x2 __attribute__((ext_vector_type(2)));

#define NPTS 4096
#define BATCH 8
#define BLK 256
#define P 8                              // own points per thread (4 f32x2)
#define NPAIR 4
#define CHUNK 256                        // staged points per chunk
#define NCHUNK (NPTS / CHUNK)            // 16
#define OWN_PER_BLK (BLK * P)            // 2048
#define OWN_BLKS (NPTS / OWN_PER_BLK)    // 2 per batch
#define BLOCKS_PER_PASS (BATCH * OWN_BLKS * NCHUNK)  // 256
#define TOTAL_BLOCKS (2 * BLOCKS_PER_PASS)           // 512
#define HALF_OWN (BATCH * NPTS)          // 32768
#define TOTAL_OWN (2 * HALF_OWN)         // 65536
#define COMBINE_BLOCKS (TOTAL_OWN / BLK) // 256
#define STREAM_PTS (BATCH * NPTS)        // 32768 per direction
#define STREAM_PAD 16
#define REPS 8                           // chunks per block (probe amplification)

struct Pt8 { f32x2 x, y, z, w; };        // 32 B, components pre-duplicated

static __device__ __forceinline__ f32x2 splat2(float v) {
    f32x2 r; r.x = v; r.y = v; return r;
}

__global__ __launch_bounds__(BLK) void chamfer_prep_kernel(
    const float* __restrict__ pred, const float* __restrict__ gt,
    Pt8* __restrict__ sA, Pt8* __restrict__ sB)
{
    const int i = blockIdx.x * BLK + threadIdx.x;
    const int b = i >> 12;
    const int m = i & (NPTS - 1);
    {
        const float* gp = gt + ((size_t)b * NPTS + m) * 3;
        float gx = gp[0], gy = gp[1], gz = gp[2];
        Pt8 e;
        e.x = splat2(-2.f * gx); e.y = splat2(-2.f * gy); e.z = splat2(-2.f * gz);
        e.w = splat2(fmaf(gx, gx, fmaf(gy, gy, gz * gz)));
        sA[i] = e;
    }
    {
        const float* pp = pred + (size_t)b * 3 * NPTS;
        float px = pp[m], py = pp[NPTS + m], pz = pp[2 * NPTS + m];
        Pt8 e;
        e.x = splat2(-2.f * px); e.y = splat2(-2.f * py); e.z = splat2(-2.f * pz);
        e.w = splat2(fmaf(px, px, fmaf(py, py, pz * pz)));
        sB[i] = e;
    }
}

// ---------- Probe A: R2's LDS-broadcast structure, REPS chunks per block ----
__global__ __launch_bounds__(BLK) void chamfer_lds_probe(
    const float* __restrict__ pred, const float* __restrict__ gt,
    float* __restrict__ partial)
{
    __shared__ float4 s[CHUNK];

    const int bid  = blockIdx.x;
    const int pass = bid / BLOCKS_PER_PASS;
    int r = bid - pass * BLOCKS_PER_PASS;
    const int c = r % NCHUNK;
    r /= NCHUNK;
    const int b = r / OWN_BLKS;
    const int j = r - b * OWN_BLKS;
    const int t = threadIdx.x;

    const float* p = pred + (size_t)b * 3 * NPTS;
    const float* g = gt   + (size_t)b * NPTS * 3;

    f32x2 X[NPAIR], Y[NPAIR], Z[NPAIR], N2[NPAIR];
    #pragma unroll
    for (int k = 0; k < P; ++k) {
        int idx = j * OWN_PER_BLK + k * BLK + t;
        float x, y, z;
        if (pass == 0) { x = p[idx]; y = p[NPTS + idx]; z = p[2 * NPTS + idx]; }
        else           { x = g[idx * 3]; y = g[idx * 3 + 1]; z = g[idx * 3 + 2]; }
        X[k >> 1][k & 1] = x; Y[k >> 1][k & 1] = y; Z[k >> 1][k & 1] = z;
        N2[k >> 1][k & 1] = fmaf(x, x, fmaf(y, y, z * z));
    }

    f32x2 A[NPAIR], B[NPAIR];
    #pragma unroll
    for (int pk = 0; pk < NPAIR; ++pk) { A[pk] = splat2(3.4e38f); B[pk] = splat2(3.4e38f); }

    for (int rep = 0; rep < REPS; ++rep) {
        const int cc = (c + rep) & (NCHUNK - 1);
        const int cbase = cc * CHUNK;
        __syncthreads();               // protect s[] from previous rep's readers
        {
            int i = t;                 // CHUNK == BLK
            if (pass == 0) {
                int gi = cbase + i;
                float gx = g[gi * 3], gy = g[gi * 3 + 1], gz = g[gi * 3 + 2];
                s[i] = make_float4(-2.f * gx, -2.f * gy, -2.f * gz,
                                   fmaf(gx, gx, fmaf(gy, gy, gz * gz)));
            } else {
                int pi = cbase + i;
                float px = p[pi], py = p[NPTS + pi], pz = p[2 * NPTS + pi];
                s[i] = make_float4(-2.f * px, -2.f * py, -2.f * pz,
                                   fmaf(px, px, fmaf(py, py, pz * pz)));
            }
        }
        __syncthreads();

        #pragma unroll 2
        for (int mm = 0; mm < CHUNK; mm += 2) {
            float4 q0 = s[mm + 0];
            float4 q1 = s[mm + 1];
            f32x2 q0x = splat2(q0.x), q0y = splat2(q0.y), q0z = splat2(q0.z), q0w = splat2(q0.w);
            f32x2 q1x = splat2(q1.x), q1y = splat2(q1.y), q1z = splat2(q1.z), q1w = splat2(q1.w);
            #pragma unroll
            for (int pk = 0; pk < NPAIR; ++pk) {
                f32x2 d0 = __builtin_elementwise_fma(X[pk], q0x,
                            __builtin_elementwise_fma(Y[pk], q0y,
                             __builtin_elementwise_fma(Z[pk], q0z, q0w)));
                A[pk] = __builtin_elementwise_min(A[pk], d0);
                f32x2 d1 = __builtin_elementwise_fma(X[pk], q1x,
                            __builtin_elementwise_fma(Y[pk], q1y,
                             __builtin_elementwise_fma(Z[pk], q1z, q1w)));
                B[pk] = __builtin_elementwise_min(B[pk], d1);
            }
        }
    }

    #pragma unroll
    for (int pk = 0; pk < NPAIR; ++pk) {
        f32x2 mn = __builtin_elementwise_min(A[pk], B[pk]);
        #pragma unroll
        for (int h = 0; h < 2; ++h) {
            int k = 2 * pk + h;
            int idx = j * OWN_PER_BLK + k * BLK + t;
            int o = pass * HALF_OWN + b * NPTS + idx;
            partial[(size_t)c * TOTAL_OWN + o] = N2[pk][h] + mn[h];
        }
    }
}

// ---------- Probe B: R6's SGPR-stream structure, REPS chunks per block ------
__global__ __launch_bounds__(BLK, 2) void chamfer_smem_probe(
    const float* __restrict__ pred, const float* __restrict__ gt,
    const Pt8* __restrict__ sA, const Pt8* __restrict__ sB,
    float* __restrict__ dummy)
{
    const int bid  = blockIdx.x;
    const int pass = bid / BLOCKS_PER_PASS;
    int r = bid - pass * BLOCKS_PER_PASS;
    const int c = r % NCHUNK;
    r /= NCHUNK;
    const int b = r / OWN_BLKS;
    const int j = r - b * OWN_BLKS;
    const int t = threadIdx.x;

    const float* p = pred + (size_t)b * 3 * NPTS;
    const float* g = gt   + (size_t)b * NPTS * 3;
    const Pt8* __restrict__ base = (pass == 0 ? sA : sB) + (size_t)b * NPTS;

    f32x2 X[NPAIR], Y[NPAIR], Z[NPAIR], N2[NPAIR];
    #pragma unroll
    for (int k = 0; k < P; ++k) {
        int idx = j * OWN_PER_BLK + k * BLK + t;
        float x, y, z;
        if (pass == 0) { x = p[idx]; y = p[NPTS + idx]; z = p[2 * NPTS + idx]; }
        else           { x = g[idx * 3]; y = g[idx * 3 + 1]; z = g[idx * 3 + 2]; }
        X[k >> 1][k & 1] = x; Y[k >> 1][k & 1] = y; Z[k >> 1][k & 1] = z;
        N2[k >> 1][k & 1] = fmaf(x, x, fmaf(y, y, z * z));
    }

    f32x2 A[NPAIR], B[NPAIR];
    #pragma unroll
    for (int pk = 0; pk < NPAIR; ++pk) { A[pk] = splat2(3.4e38f); B[pk] = splat2(3.4e38f); }

    #define COMP(q, ACC)                                                        \
        do {                                                                    \
            _Pragma("unroll")                                                   \
            for (int pk = 0; pk < NPAIR; ++pk) {                                \
                f32x2 d = __builtin_elementwise_fma((q).x, X[pk],               \
                           __builtin_elementwise_fma((q).y, Y[pk],              \
                            __builtin_elementwise_fma((q).z, Z[pk], (q).w)));   \
                ACC[pk] = __builtin_elementwise_min(ACC[pk], d);                \
            }                                                                   \
        } while (0)

    for (int rep = 0; rep < REPS; ++rep) {
        const int cc = (c + rep) & (NCHUNK - 1);
        const Pt8* __restrict__ st = base + cc * CHUNK;
        Pt8 a0 = st[0], a1 = st[1], a2 = st[2], a3 = st[3];
        Pt8 b0, b1, b2, b3;
        #pragma unroll 1
        for (int mm = 0; mm < CHUNK; mm += 8) {
            b0 = st[mm + 4]; b1 = st[mm + 5]; b2 = st[mm + 6]; b3 = st[mm + 7];
            COMP(a0, A); COMP(a1, B); COMP(a2, A); COMP(a3, B);
            a0 = st[mm + 8]; a1 = st[mm + 9]; a2 = st[mm + 10]; a3 = st[mm + 11];
            COMP(b0, A); COMP(b1, B); COMP(b2, A); COMP(b3, B);
        }
    }
    #undef COMP

    #pragma unroll
    for (int pk = 0; pk < NPAIR; ++pk) {
        f32x2 mn = __builtin_elementwise_min(A[pk], B[pk]);
        #pragma unroll
        for (int h = 0; h < 2; ++h) {
            int k = 2 * pk + h;
            int idx = j * OWN_PER_BLK + k * BLK + t;
            int o = pass * HALF_OWN + b * NPTS + idx;
            dummy[(size_t)c * TOTAL_OWN + o] = N2[pk][h] + mn[h];
        }
    }
}

__global__ __launch_bounds__(BLK) void chamfer_combine_kernel(
    const float* __restrict__ partial, float* __restrict__ bsum)
{
    __shared__ float red[BLK / 64];
    const int t = threadIdx.x;
    const int o = blockIdx.x * BLK + t;
    float v = 3.4e38f;
    #pragma unroll
    for (int c = 0; c < NCHUNK; ++c)
        v = fminf(v, partial[(size_t)c * TOTAL_OWN + o]);
    #pragma unroll
    for (int off = 32; off > 0; off >>= 1)
        v += __shfl_down(v, off, 64);
    if ((t & 63) == 0) red[t >> 6] = v;
    __syncthreads();
    if (t == 0) bsum[blockIdx.x] = red[0] + red[1] + red[2] + red[3];
}

__global__ __launch_bounds__(COMBINE_BLOCKS) void chamfer_final_kernel(
    const float* __restrict__ bsum, float* __restrict__ out)
{
    __shared__ float red[COMBINE_BLOCKS / 64];
    const int t = threadIdx.x;
    float v = bsum[t];
    #pragma unroll
    for (int off = 32; off > 0; off >>= 1)
        v += __shfl_down(v, off, 64);
    if ((t & 63) == 0) red[t >> 6] = v;
    __syncthreads();
    if (t == 0) {
        float s = 0.f;
        #pragma unroll
        for (int w = 0; w < COMBINE_BLOCKS / 64; ++w) s += red[w];
        out[0] = s * (1.0f / ((float)NPTS * (float)BATCH));
    }
}

extern "C" void kernel_launch(void* const* d_in, const int* in_sizes, int n_in,
                              void* d_out, int out_size, void* d_ws, size_t ws_size,
                              hipStream_t stream) {
    const float* pred = (const float*)d_in[0];  // [8,3,4096]
    const float* gt   = (const float*)d_in[1];  // [8,4096,3]
    float* out = (float*)d_out;

    Pt8*   sA      = (Pt8*)d_ws;
    Pt8*   sB      = sA + (STREAM_PTS + STREAM_PAD);
    float* partial = (float*)(sB + (STREAM_PTS + STREAM_PAD));      // 4 MB
    float* dummy   = partial + (size_t)NCHUNK * TOTAL_OWN;          // 4 MB
    float* bsum    = dummy + (size_t)NCHUNK * TOTAL_OWN;

    chamfer_prep_kernel<<<STREAM_PTS / BLK, BLK, 0, stream>>>(pred, gt, sA, sB);
    chamfer_lds_probe<<<TOTAL_BLOCKS, BLK, 0, stream>>>(pred, gt, partial);
    chamfer_smem_probe<<<TOTAL_BLOCKS, BLK, 0, stream>>>(pred, gt, sA, sB, dummy);
    chamfer_combine_kernel<<<COMBINE_BLOCKS, BLK, 0, stream>>>(partial, bsum);
    chamfer_final_kernel<<<1, COMBINE_BLOCKS, 0, stream>>>(bsum, out);
}

// Round 8
// 47.711 us; speedup vs baseline: 7.1274x; 7.1274x over previous
//
#include <hip/hip_runtime.h>

#define NPTS 4096
#define BATCH 8
#define BLK 256
#define P 16                              // own points per thread
#define STG 64                            // staged points per block (1 KB LDS)
#define SLOTS (NPTS / STG)                // 64 staged tiles per (pass,batch)
#define BLOCKS_PER_PASS (BATCH * SLOTS)   // 512
#define TOTAL_BLOCKS (2 * BLOCKS_PER_PASS)// 1024 = 4 blocks/CU
#define HALF_OWN (BATCH * NPTS)           // 32768
#define TOTAL_OWN (2 * HALF_OWN)          // 65536
#define COMBINE_BLOCKS (TOTAL_OWN / BLK)  // 256

// Each block: ALL 4096 own points of one (pass,batch) x one 64-pt staged tile.
// LDS entry: (-2qx,-2qy,-2qz,||q||^2); D = ||p||^2 + (||q||^2 - 2 p.q).
// ||p||^2 added at epilogue (recomputed, not held in regs).
// Inner: per 2 staged pts, per own pt: 6 v_fma_f32 + 1 v_min3_f32.
__global__ __launch_bounds__(BLK, 4) void chamfer_partial_kernel(
    const float* __restrict__ pred,   // [B,3,N]
    const float* __restrict__ gt,     // [B,M,3]
    float* __restrict__ partial)      // [SLOTS][TOTAL_OWN]
{
    __shared__ float4 s[STG];

    const int bid  = blockIdx.x;
    const int pass = bid >> 9;            // bid / BLOCKS_PER_PASS
    const int r    = bid & 511;
    const int b    = r >> 6;              // batch
    const int c    = r & 63;              // staged tile
    const int t    = threadIdx.x;

    const float* p = pred + (size_t)b * 3 * NPTS;
    const float* g = gt   + (size_t)b * NPTS * 3;

    // Stage 64 prescaled "other" points (threads 0..63).
    if (t < STG) {
        int i = c * STG + t;
        float qx, qy, qz;
        if (pass == 0) { qx = g[i * 3 + 0]; qy = g[i * 3 + 1]; qz = g[i * 3 + 2]; }
        else           { qx = p[i]; qy = p[NPTS + i]; qz = p[2 * NPTS + i]; }
        s[t] = make_float4(-2.f * qx, -2.f * qy, -2.f * qz,
                           fmaf(qx, qx, fmaf(qy, qy, qz * qz)));
    }

    // Own points: 16 per thread (whole 4096-pt set per block).
    float x[P], y[P], z[P];
    #pragma unroll
    for (int k = 0; k < P; ++k) {
        int idx = k * BLK + t;
        if (pass == 0) { x[k] = p[idx]; y[k] = p[NPTS + idx]; z[k] = p[2 * NPTS + idx]; }
        else           { x[k] = g[idx * 3 + 0]; y[k] = g[idx * 3 + 1]; z[k] = g[idx * 3 + 2]; }
    }
    __syncthreads();

    float acc[P];
    #pragma unroll
    for (int k = 0; k < P; ++k) acc[k] = 3.4e38f;

    #pragma unroll 2
    for (int ss = 0; ss < STG; ss += 2) {
        float4 q0 = s[ss + 0];
        float4 q1 = s[ss + 1];
        #pragma unroll
        for (int k = 0; k < P; ++k) {
            float d0 = fmaf(x[k], q0.x, fmaf(y[k], q0.y, fmaf(z[k], q0.z, q0.w)));
            float d1 = fmaf(x[k], q1.x, fmaf(y[k], q1.y, fmaf(z[k], q1.z, q1.w)));
            acc[k] = fminf(fminf(d0, d1), acc[k]);   // -> v_min3_f32
        }
    }

    // Epilogue: add ||p||^2 (recomputed) and store one partial per own point.
    #pragma unroll
    for (int k = 0; k < P; ++k) {
        int idx = k * BLK + t;
        int o = pass * HALF_OWN + b * NPTS + idx;
        float n2 = fmaf(x[k], x[k], fmaf(y[k], y[k], z[k] * z[k]));
        partial[(size_t)c * TOTAL_OWN + o] = n2 + acc[k];
    }
}

// Min over the 64 slots per own point, then deterministic block partial sums.
__global__ __launch_bounds__(BLK) void chamfer_combine_kernel(
    const float* __restrict__ partial, float* __restrict__ bsum)
{
    __shared__ float red[BLK / 64];
    const int t = threadIdx.x;
    const int o = blockIdx.x * BLK + t;
    float v = 3.4e38f;
    #pragma unroll 8
    for (int cc = 0; cc < SLOTS; ++cc)
        v = fminf(v, partial[(size_t)cc * TOTAL_OWN + o]);
    #pragma unroll
    for (int off = 32; off > 0; off >>= 1)
        v += __shfl_down(v, off, 64);
    if ((t & 63) == 0) red[t >> 6] = v;
    __syncthreads();
    if (t == 0) bsum[blockIdx.x] = red[0] + red[1] + red[2] + red[3];
}

__global__ __launch_bounds__(COMBINE_BLOCKS) void chamfer_final_kernel(
    const float* __restrict__ bsum, float* __restrict__ out)
{
    __shared__ float red[COMBINE_BLOCKS / 64];
    const int t = threadIdx.x;
    float v = bsum[t];
    #pragma unroll
    for (int off = 32; off > 0; off >>= 1)
        v += __shfl_down(v, off, 64);
    if ((t & 63) == 0) red[t >> 6] = v;
    __syncthreads();
    if (t == 0) {
        float s = 0.f;
        #pragma unroll
        for (int w = 0; w < COMBINE_BLOCKS / 64; ++w) s += red[w];
        // loss = (sum of all mins) / (NPTS * BATCH)   (N == M)
        out[0] = s * (1.0f / ((float)NPTS * (float)BATCH));
    }
}

extern "C" void kernel_launch(void* const* d_in, const int* in_sizes, int n_in,
                              void* d_out, int out_size, void* d_ws, size_t ws_size,
                              hipStream_t stream) {
    const float* pred = (const float*)d_in[0];  // [8,3,4096]
    const float* gt   = (const float*)d_in[1];  // [8,4096,3]
    float* out = (float*)d_out;

    float* partial = (float*)d_ws;                                  // 64*65536 floats = 16 MB
    float* bsum    = partial + (size_t)SLOTS * TOTAL_OWN;           // 256 floats

    chamfer_partial_kernel<<<TOTAL_BLOCKS, BLK, 0, stream>>>(pred, gt, partial);
    chamfer_combine_kernel<<<COMBINE_BLOCKS, BLK, 0, stream>>>(partial, bsum);
    chamfer_final_kernel<<<1, COMBINE_BLOCKS, 0, stream>>>(bsum, out);
}

// Round 9
// 32.624 us; speedup vs baseline: 10.4234x; 1.4624x over previous
//
#include <hip/hip_runtime.h>

#define NPTS 4096
#define BATCH 8
#define BLK 256
#define P 4                               // own points per thread
#define CHUNK 256                         // staged points per chunk (== BLK)
#define REPS 2                            // chunks folded per block
#define NSLOT 8                           // chunk-groups -> partial slots
#define OWN_PER_BLK (BLK * P)             // 1024
#define OWN_BLKS (NPTS / OWN_PER_BLK)     // 4 per batch
#define BLOCKS_PER_PASS (BATCH * OWN_BLKS * NSLOT)   // 256
#define TOTAL_BLOCKS (2 * BLOCKS_PER_PASS)           // 512 = 2 blocks/CU
#define HALF_OWN (BATCH * NPTS)           // 32768
#define TOTAL_OWN (2 * HALF_OWN)          // 65536
#define COMBINE_BLOCKS (TOTAL_OWN / BLK)  // 256

// Each block: P*BLK own points x (REPS*CHUNK) staged points, min folded in
// registers across reps. LDS entry: (-2qx,-2qy,-2qz,||q||^2);
// D = ||p||^2 + (||q||^2 - 2 p.q); ||p||^2 added at epilogue.
// Inner: per 2 staged pts per own pt: 6 v_fma_f32 + 1 v_min3_f32.
__global__ __launch_bounds__(BLK, 2) void chamfer_partial_kernel(
    const float* __restrict__ pred,   // [B,3,N]
    const float* __restrict__ gt,     // [B,M,3]
    float* __restrict__ partial)      // [NSLOT][TOTAL_OWN]
{
    __shared__ float4 s[CHUNK];

    const int bid  = blockIdx.x;
    const int pass = bid / BLOCKS_PER_PASS;
    int r = bid - pass * BLOCKS_PER_PASS;
    const int c = r % NSLOT;
    r /= NSLOT;
    const int b = r / OWN_BLKS;
    const int j = r - b * OWN_BLKS;
    const int t = threadIdx.x;

    const float* p = pred + (size_t)b * 3 * NPTS;
    const float* g = gt   + (size_t)b * NPTS * 3;

    // Own points (coalesced in both layouts).
    float x[P], y[P], z[P];
    #pragma unroll
    for (int k = 0; k < P; ++k) {
        int idx = j * OWN_PER_BLK + k * BLK + t;
        if (pass == 0) { x[k] = p[idx]; y[k] = p[NPTS + idx]; z[k] = p[2 * NPTS + idx]; }
        else           { x[k] = g[idx * 3 + 0]; y[k] = g[idx * 3 + 1]; z[k] = g[idx * 3 + 2]; }
    }

    // Prefetch first chunk's staging values into registers.
    float qx, qy, qz;
    {
        int i = (c * REPS) * CHUNK + t;
        if (pass == 0) { qx = g[i * 3 + 0]; qy = g[i * 3 + 1]; qz = g[i * 3 + 2]; }
        else           { qx = p[i]; qy = p[NPTS + i]; qz = p[2 * NPTS + i]; }
    }

    float acc[P];
    #pragma unroll
    for (int k = 0; k < P; ++k) acc[k] = 3.4e38f;

    #pragma unroll
    for (int rep = 0; rep < REPS; ++rep) {
        __syncthreads();                      // protect s[] from previous readers
        s[t] = make_float4(-2.f * qx, -2.f * qy, -2.f * qz,
                           fmaf(qx, qx, fmaf(qy, qy, qz * qz)));
        __syncthreads();

        // Prefetch next chunk's staging values during this chunk's compute.
        if (rep + 1 < REPS) {
            int i = (c * REPS + rep + 1) * CHUNK + t;
            if (pass == 0) { qx = g[i * 3 + 0]; qy = g[i * 3 + 1]; qz = g[i * 3 + 2]; }
            else           { qx = p[i]; qy = p[NPTS + i]; qz = p[2 * NPTS + i]; }
        }

        #pragma unroll 2
        for (int ss = 0; ss < CHUNK; ss += 2) {
            float4 q0 = s[ss + 0];
            float4 q1 = s[ss + 1];
            #pragma unroll
            for (int k = 0; k < P; ++k) {
                float d0 = fmaf(x[k], q0.x, fmaf(y[k], q0.y, fmaf(z[k], q0.z, q0.w)));
                float d1 = fmaf(x[k], q1.x, fmaf(y[k], q1.y, fmaf(z[k], q1.z, q1.w)));
                acc[k] = fminf(fminf(d0, d1), acc[k]);   // -> v_min3_f32
            }
        }
    }

    // Epilogue: add ||p||^2 (recomputed) and store one partial per own point.
    #pragma unroll
    for (int k = 0; k < P; ++k) {
        int idx = j * OWN_PER_BLK + k * BLK + t;
        int o = pass * HALF_OWN + b * NPTS + idx;
        float n2 = fmaf(x[k], x[k], fmaf(y[k], y[k], z[k] * z[k]));
        partial[(size_t)c * TOTAL_OWN + o] = n2 + acc[k];
    }
}

// Min over the 8 slots per own point, then deterministic block partial sums.
__global__ __launch_bounds__(BLK) void chamfer_combine_kernel(
    const float* __restrict__ partial, float* __restrict__ bsum)
{
    __shared__ float red[BLK / 64];
    const int t = threadIdx.x;
    const int o = blockIdx.x * BLK + t;
    float v = 3.4e38f;
    #pragma unroll
    for (int cc = 0; cc < NSLOT; ++cc)
        v = fminf(v, partial[(size_t)cc * TOTAL_OWN + o]);
    #pragma unroll
    for (int off = 32; off > 0; off >>= 1)
        v += __shfl_down(v, off, 64);
    if ((t & 63) == 0) red[t >> 6] = v;
    __syncthreads();
    if (t == 0) bsum[blockIdx.x] = red[0] + red[1] + red[2] + red[3];
}

__global__ __launch_bounds__(COMBINE_BLOCKS) void chamfer_final_kernel(
    const float* __restrict__ bsum, float* __restrict__ out)
{
    __shared__ float red[COMBINE_BLOCKS / 64];
    const int t = threadIdx.x;
    float v = bsum[t];
    #pragma unroll
    for (int off = 32; off > 0; off >>= 1)
        v += __shfl_down(v, off, 64);
    if ((t & 63) == 0) red[t >> 6] = v;
    __syncthreads();
    if (t == 0) {
        float s = 0.f;
        #pragma unroll
        for (int w = 0; w < COMBINE_BLOCKS / 64; ++w) s += red[w];
        // loss = (sum of all mins) / (NPTS * BATCH)   (N == M)
        out[0] = s * (1.0f / ((float)NPTS * (float)BATCH));
    }
}

extern "C" void kernel_launch(void* const* d_in, const int* in_sizes, int n_in,
                              void* d_out, int out_size, void* d_ws, size_t ws_size,
                              hipStream_t stream) {
    const float* pred = (const float*)d_in[0];  // [8,3,4096]
    const float* gt   = (const float*)d_in[1];  // [8,4096,3]
    float* out = (float*)d_out;

    float* partial = (float*)d_ws;                                  // 8*65536 floats = 2 MB
    float* bsum    = partial + (size_t)NSLOT * TOTAL_OWN;           // 256 floats

    chamfer_partial_kernel<<<TOTAL_BLOCKS, BLK, 0, stream>>>(pred, gt, partial);
    chamfer_combine_kernel<<<COMBINE_BLOCKS, BLK, 0, stream>>>(partial, bsum);
    chamfer_final_kernel<<<1, COMBINE_BLOCKS, 0, stream>>>(bsum, out);
}